// Round 1
// baseline (253.694 us; speedup 1.0000x reference)
//
#include <hip/hip_runtime.h>

// Problem constants (match reference):
//   x:       [256, 3, 224, 224] fp32
//   patch:   [1, 3, 30, 30]     fp32
//   offsets: [256, 2]           int32, each in [0, 194)
//   out = x, with patch added at (r, c) per sample.
#define ISIZE 224
#define PSIZE 30
#define BATCH 256
#define NCH   3

// Derived (all exact, no remainders):
//   per-image floats  = 3*224*224 = 150528  -> 37632 float4
//   per-chan  floats  = 224*224   = 50176   -> 12544 float4
//   per-row   floats  = 224                 -> 56    float4
//   total float4      = 256*37632 = 9,633,792 = 37632 blocks * 256 threads

__global__ __launch_bounds__(256)
void RandomPrompter_64982855189232_kernel(const float* __restrict__ x,
                                          const float* __restrict__ patch,
                                          const int* __restrict__ offsets,
                                          float* __restrict__ out) {
    constexpr int PER_IMG4 = NCH * ISIZE * ISIZE / 4;  // 37632
    constexpr int PER_CH4  = ISIZE * ISIZE / 4;        // 12544
    constexpr int PER_ROW4 = ISIZE / 4;                // 56

    const int i4 = blockIdx.x * blockDim.x + threadIdx.x;

    const float4* __restrict__ x4 = (const float4*)x;
    float4* __restrict__ o4 = (float4*)out;

    // Streaming load first so the VMEM request is in flight during index math.
    float4 v = x4[i4];

    // Decode (b, ch, row, col). Compiler strength-reduces these const divides.
    const int b    = i4 / PER_IMG4;
    const int rem  = i4 - b * PER_IMG4;
    const int ch   = rem / PER_CH4;
    const int rem2 = rem - ch * PER_CH4;
    const int row  = rem2 / PER_ROW4;
    const int col  = (rem2 - row * PER_ROW4) * 4;

    // Per-sample patch origin. Uniform across the block (each 256-thread block
    // lies entirely inside one image) -> L1 broadcast.
    const int r = offsets[2 * b];
    const int c = offsets[2 * b + 1];

    const int pr = row - r;
    if (pr >= 0 && pr < PSIZE) {
        const float* __restrict__ prow = patch + (ch * PSIZE + pr) * PSIZE;
        float* vf = (float*)&v;
#pragma unroll
        for (int j = 0; j < 4; ++j) {
            const int pc = col + j - c;
            if (pc >= 0 && pc < PSIZE) {
                vf[j] += prow[pc];
            }
        }
    }
    o4[i4] = v;
}

extern "C" void kernel_launch(void* const* d_in, const int* in_sizes, int n_in,
                              void* d_out, int out_size, void* d_ws, size_t ws_size,
                              hipStream_t stream) {
    const float* x       = (const float*)d_in[0];
    const float* patch   = (const float*)d_in[1];
    const int*   offsets = (const int*)d_in[2];
    float*       out     = (float*)d_out;

    constexpr int TOTAL4 = BATCH * NCH * ISIZE * ISIZE / 4;  // 9,633,792
    constexpr int BLOCK  = 256;
    constexpr int GRID   = TOTAL4 / BLOCK;                   // 37,632 (exact)

    RandomPrompter_64982855189232_kernel<<<GRID, BLOCK, 0, stream>>>(x, patch, offsets, out);
}